// Round 2
// baseline (301.949 us; speedup 1.0000x reference)
//
#include <hip/hip_runtime.h>
#include <math.h>

// Capsule routing without materializing u_hat (537 MB).
//   o[b,n,:] = W_n * (sum_i c[b,n,i] u[b,i,:])
//   logits[b,n,i] = u[b,i,:] . (W_n^T o_norm[b,n,:])  = u . t
// R2: fused logits+softmax+aggregate kernel (k_route) — no bl round-trip,
// u read once per routing iteration (L3-resident). k_ot stages W_n in LDS
// once per 8 batches.

#define B   64
#define IN  1024
#define ID  256
#define NC  32
#define DC  64
#define CH  8
#define RIT (IN / CH)   // 128 i per chunk

// ---------------------------------------------------------------------------
// sp0[c][b][d] = sum over i-chunk c of u[b][i][d]
__global__ __launch_bounds__(256) void k_sumu(const float* __restrict__ u,
                                              float* __restrict__ sp0) {
    const int c = blockIdx.x, b = blockIdx.y;
    const int d = threadIdx.x;
    const float* up = u + ((size_t)b * IN + (size_t)c * RIT) * ID + d;
    float acc = 0.f;
#pragma unroll 8
    for (int i = 0; i < RIT; ++i) acc += up[(size_t)i * ID];
    sp0[(c * B + b) * ID + d] = acc;
}

// ---------------------------------------------------------------------------
// Block = (n, group of 8 b). W_n staged once in LDS (64 KB), reused 8x.
// Per b: s = reduce(partials); o = W_n s; then
//   mode 0: src=sp0 (uniform c=1/32), normalize, t = W_n^T o_norm
//   mode 1: src=sp,                   normalize, t = W_n^T o_norm
//   mode 2: src=sp, squash(o) -> out
__global__ __launch_bounds__(256) void k_ot(const float* __restrict__ W,
                                            const float* __restrict__ src,
                                            float* __restrict__ tout,
                                            const int mode) {
    const int n = blockIdx.x, b0 = blockIdx.y * 8;
    __shared__ float Ws[DC * ID];     // 64 KB
    __shared__ float s_lds[ID];
    __shared__ float o_lds[DC];
    __shared__ float on_lds[DC];
    const int tid = threadIdx.x;
    const int wave = tid >> 6, lane = tid & 63;

    // stage W_n (float4, coalesced): 4096 float4 / 256 threads = 16 each
    {
        const float4* Wn4 = (const float4*)(W + (size_t)n * DC * ID);
        float4* Ws4 = (float4*)Ws;
#pragma unroll
        for (int j = 0; j < (DC * ID / 4) / 256; ++j)
            Ws4[tid + j * 256] = Wn4[tid + j * 256];
    }

    for (int bb = 0; bb < 8; ++bb) {
        const int b = b0 + bb;
        float sv = 0.f;
        if (mode == 0) {
#pragma unroll
            for (int c = 0; c < CH; ++c) sv += src[(c * B + b) * ID + tid];
            sv *= (1.0f / NC);
        } else {
#pragma unroll
            for (int c = 0; c < CH; ++c)
                sv += src[((size_t)(c * B + b) * NC + n) * ID + tid];
        }
        s_lds[tid] = sv;
        __syncthreads();   // A: s (and Ws on first iter) ready

        // o[d] = Ws[d,:] . s — wave per 16 rows, lane sums 4 strided, shuffle
#pragma unroll 4
        for (int rr = 0; rr < 16; ++rr) {
            const int d = wave * 16 + rr;
            const float* wrow = Ws + d * ID;
            float p = wrow[lane]       * s_lds[lane]
                    + wrow[lane + 64]  * s_lds[lane + 64]
                    + wrow[lane + 128] * s_lds[lane + 128]
                    + wrow[lane + 192] * s_lds[lane + 192];
#pragma unroll
            for (int off = 32; off > 0; off >>= 1) p += __shfl_down(p, off);
            if (lane == 0) o_lds[d] = p;
        }
        __syncthreads();   // B: o ready

        if (mode == 2) {
            if (tid < DC) {
                float v = o_lds[tid];
                float sq = v * v;
#pragma unroll
                for (int off = 32; off > 0; off >>= 1) sq += __shfl_down(sq, off);
                sq = __shfl(sq, 0) + 1e-7f;
                const float sc = sqrtf(sq) / (0.5f + sq);
                tout[(size_t)(b * NC + n) * DC + tid] = v * sc;
            }
            continue;  // o_lds overwritten only after next sync A — safe
        }

        // F.normalize
        if (tid < DC) {
            float v = o_lds[tid];
            float sq = v * v;
#pragma unroll
            for (int off = 32; off > 0; off >>= 1) sq += __shfl_down(sq, off);
            sq = __shfl(sq, 0);
            on_lds[tid] = v / fmaxf(sqrtf(sq), 1e-12f);
        }
        __syncthreads();   // C: on ready

        // t[k] = sum_d Ws[d][k] * on[d] — lane-consecutive LDS, broadcast on
        float acc = 0.f;
        const float* wc = Ws + tid;
#pragma unroll
        for (int d = 0; d < DC; ++d) acc += wc[d * ID] * on_lds[d];
        tout[((size_t)b * NC + n) * ID + tid] = acc;
    }
}

// ---------------------------------------------------------------------------
// Fused: logits tile (128 i x 32 n, K=256) -> softmax over n -> aggregate
// sp[c][b][n][d] = sum_{i in chunk} c[n,i] * u[b,i,d]
__global__ __launch_bounds__(256) void k_route(const float* __restrict__ u,
                                               const float* __restrict__ t,
                                               float* __restrict__ sp) {
    const int c = blockIdx.x, b = blockIdx.y;
    const int iBase = c * RIT;
    __shared__ float Ts[ID][36];     // t[b] transposed: Ts[k][n]
    __shared__ float cl[RIT][36];    // logits -> coefficients
    __shared__ float Us[16][132];    // u chunk transposed: Us[k][i]
    const int tid = threadIdx.x;

    // Ts[k][n] = t[b][n][k]  (coalesced global, k=tid)
    {
        const float* tb = t + (size_t)b * NC * ID;
#pragma unroll
        for (int n = 0; n < NC; ++n) Ts[tid][n] = tb[(size_t)n * ID + tid];
    }

    // phase 1: logits GEMM (R1 k_bl structure, output to LDS)
    const int q = tid >> 3, r = tid & 7;
    const float* ub = u + ((size_t)b * IN + iBase) * ID;
    float acc4[4][4] = {{0.f}};
    for (int kc = 0; kc < ID / 16; ++kc) {
        __syncthreads();   // Ts ready (iter 0) / prior Us consumed
#pragma unroll
        for (int rep = 0; rep < 2; ++rep) {
            const int f = tid + rep * 256;
            const int i = f >> 2, c4 = f & 3;
            const float4 v = *(const float4*)(ub + (size_t)i * ID + kc * 16 + c4 * 4);
            Us[c4 * 4 + 0][i] = v.x;
            Us[c4 * 4 + 1][i] = v.y;
            Us[c4 * 4 + 2][i] = v.z;
            Us[c4 * 4 + 3][i] = v.w;
        }
        __syncthreads();
#pragma unroll
        for (int k = 0; k < 16; ++k) {
            const float4 a4 = *(const float4*)&Us[k][q * 4];
            const float4 b4 = *(const float4*)&Ts[kc * 16 + k][r * 4];
            const float av[4] = {a4.x, a4.y, a4.z, a4.w};
            const float bv[4] = {b4.x, b4.y, b4.z, b4.w};
#pragma unroll
            for (int ii = 0; ii < 4; ++ii)
#pragma unroll
                for (int jj = 0; jj < 4; ++jj) acc4[ii][jj] += av[ii] * bv[jj];
        }
    }
#pragma unroll
    for (int ii = 0; ii < 4; ++ii)
#pragma unroll
        for (int jj = 0; jj < 4; ++jj)
            cl[q * 4 + ii][r * 4 + jj] = acc4[ii][jj];
    __syncthreads();

    // phase 2: softmax over 32 n per i (2 threads/i, 16 each)
    {
        const int i = tid >> 1, half = tid & 1;
        float v[16];
#pragma unroll
        for (int j = 0; j < 16; ++j) v[j] = cl[i][half * 16 + j];
        float mx = v[0];
#pragma unroll
        for (int j = 1; j < 16; ++j) mx = fmaxf(mx, v[j]);
        mx = fmaxf(mx, __shfl_xor(mx, 1));
        float sum = 0.f;
#pragma unroll
        for (int j = 0; j < 16; ++j) { v[j] = __expf(v[j] - mx); sum += v[j]; }
        sum += __shfl_xor(sum, 1);
        const float inv = 1.0f / sum;
#pragma unroll
        for (int j = 0; j < 16; ++j) cl[i][half * 16 + j] = v[j] * inv;
    }
    __syncthreads();

    // phase 3: aggregate. thread owns 4 d (float4) x 8 n (wave-uniform -> LDS
    // broadcast). u tile re-read from L2 (just fetched in phase 1).
    const int d4 = tid & 63;
    const int ng = tid >> 6;
    float acc[8][4] = {{0.f}};
    const float* up = ub + d4 * 4;
#pragma unroll 4
    for (int i = 0; i < RIT; ++i) {
        const float4 uv = *(const float4*)(up + (size_t)i * ID);
        const float4 c0 = *(const float4*)&cl[i][ng * 8];
        const float4 c1 = *(const float4*)&cl[i][ng * 8 + 4];
        const float cv[8] = {c0.x, c0.y, c0.z, c0.w, c1.x, c1.y, c1.z, c1.w};
        const float uvv[4] = {uv.x, uv.y, uv.z, uv.w};
#pragma unroll
        for (int j = 0; j < 8; ++j)
#pragma unroll
            for (int x = 0; x < 4; ++x) acc[j][x] += cv[j] * uvv[x];
    }
    float* spb = sp + (size_t)(c * B + b) * NC * ID;
#pragma unroll
    for (int j = 0; j < 8; ++j)
        *(float4*)&spb[(size_t)(ng * 8 + j) * ID + d4 * 4] =
            make_float4(acc[j][0], acc[j][1], acc[j][2], acc[j][3]);
}

// ---------------------------------------------------------------------------
extern "C" void kernel_launch(void* const* d_in, const int* in_sizes, int n_in,
                              void* d_out, int out_size, void* d_ws, size_t ws_size,
                              hipStream_t stream) {
    const float* u = (const float*)d_in[0];   // [B][IN][ID]
    const float* W = (const float*)d_in[1];   // [NC*DC][ID]
    float* out = (float*)d_out;               // [B][NC][DC]

    float* ws  = (float*)d_ws;
    float* t   = ws;                                   // B*NC*ID   = 2 MB
    float* sp  = t  + (size_t)B * NC * ID;             // CH*B*NC*ID= 16 MB
    float* sp0 = sp + (size_t)CH * B * NC * ID;        // CH*B*ID   = 0.5 MB

    const dim3 blk(256);

    // iteration 0 (uniform c = 1/32)
    k_sumu <<<dim3(CH, B),      blk, 0, stream>>>(u, sp0);
    k_ot   <<<dim3(NC, B / 8),  blk, 0, stream>>>(W, sp0, t, 0);
    // iteration 1
    k_route<<<dim3(CH, B),      blk, 0, stream>>>(u, t, sp);
    k_ot   <<<dim3(NC, B / 8),  blk, 0, stream>>>(W, sp, t, 1);
    // iteration 2
    k_route<<<dim3(CH, B),      blk, 0, stream>>>(u, t, sp);
    k_ot   <<<dim3(NC, B / 8),  blk, 0, stream>>>(W, sp, out, 2);
}

// Round 3
// 244.525 us; speedup vs baseline: 1.2348x; 1.2348x over previous
//
#include <hip/hip_runtime.h>
#include <math.h>

// Capsule routing without materializing u_hat.
//   o[b,n,:] = W_n * (sum_i c[b,n,i] u[b,i,:])
//   logits[b,i,n] = u[b,i,:] . t[b,n,:],  t = W_n^T o_norm
// R3: k_ot = wave-per-(b,n), no LDS, no barriers (R2's was 47us at 7% VALU).
//     k_route = double-buffered Us staging, 1 barrier/chunk, prefetch overlap.

#define B   64
#define IN  1024
#define ID  256
#define NC  32
#define DC  64
#define CH  8
#define RIT (IN / CH)   // 128 i per chunk

// ---------------------------------------------------------------------------
// sp0[c][b][d] = sum over i-chunk c of u[b][i][d]
__global__ __launch_bounds__(256) void k_sumu(const float* __restrict__ u,
                                              float* __restrict__ sp0) {
    const int c = blockIdx.x, b = blockIdx.y;
    const int d = threadIdx.x;
    const float* up = u + ((size_t)b * IN + (size_t)c * RIT) * ID + d;
    float acc = 0.f;
#pragma unroll 8
    for (int i = 0; i < RIT; ++i) acc += up[(size_t)i * ID];
    sp0[(c * B + b) * ID + d] = acc;
}

// ---------------------------------------------------------------------------
// One wave per (b,n). Block = 4 waves sharing n (L1 reuse of W_n rows).
// Lane l holds s[4l..4l+3] (float4). o[d] computed via coalesced W-row loads
// + butterfly reduce, lands in lane d. No LDS, no __syncthreads.
//   mode 0: src=sp0 (uniform c=1/32) -> normalize -> t
//   mode 1: src=sp                    -> normalize -> t
//   mode 2: src=sp                    -> squash -> out
__global__ __launch_bounds__(256) void k_ot(const float* __restrict__ W,
                                            const float* __restrict__ src,
                                            float* __restrict__ tout,
                                            const int mode) {
    const int n = blockIdx.x;
    const int b = blockIdx.y * 4 + (threadIdx.x >> 6);
    const int lane = threadIdx.x & 63;
    const float* Wn = W + (size_t)n * DC * ID;

    // s-reduce: 8 coalesced float4 loads
    float sx = 0.f, sy = 0.f, sz = 0.f, sw = 0.f;
    if (mode == 0) {
        const float4* p = (const float4*)src;
#pragma unroll
        for (int c = 0; c < CH; ++c) {
            const float4 v = p[(size_t)(c * B + b) * (ID / 4) + lane];
            sx += v.x; sy += v.y; sz += v.z; sw += v.w;
        }
        sx *= (1.0f / NC); sy *= (1.0f / NC); sz *= (1.0f / NC); sw *= (1.0f / NC);
    } else {
        const float4* p = (const float4*)src;
#pragma unroll
        for (int c = 0; c < CH; ++c) {
            const float4 v = p[((size_t)(c * B + b) * NC + n) * (ID / 4) + lane];
            sx += v.x; sy += v.y; sz += v.z; sw += v.w;
        }
    }

    // o-phase: row d read coalesced (lane l gets k=4l..4l+3); butterfly sum;
    // lane d keeps o[d].
    float o = 0.f;
#pragma unroll 8
    for (int d = 0; d < DC; ++d) {
        const float4 w4 = *(const float4*)(Wn + (size_t)d * ID + lane * 4);
        float psum = w4.x * sx + w4.y * sy + w4.z * sz + w4.w * sw;
#pragma unroll
        for (int off = 32; off > 0; off >>= 1) psum += __shfl_xor(psum, off);
        if (lane == d) o = psum;
    }

    // ||o||^2 via butterfly (all lanes get total)
    float sq = o * o;
#pragma unroll
    for (int off = 32; off > 0; off >>= 1) sq += __shfl_xor(sq, off);

    if (mode == 2) {
        const float s2 = sq + 1e-7f;
        const float sc = sqrtf(s2) / (0.5f + s2);
        tout[(size_t)(b * NC + n) * DC + lane] = o * sc;   // 256B coalesced
        return;
    }

    // F.normalize: lane d holds on[d]
    const float on = o / fmaxf(sqrtf(sq), 1e-12f);

    // t-phase: lane owns k-quad; per d broadcast on[d] via shuffle
    float tx = 0.f, ty = 0.f, tz = 0.f, tw = 0.f;
#pragma unroll 8
    for (int d = 0; d < DC; ++d) {
        const float4 w4 = *(const float4*)(Wn + (size_t)d * ID + lane * 4);
        const float od = __shfl(on, d);
        tx += w4.x * od; ty += w4.y * od; tz += w4.z * od; tw += w4.w * od;
    }
    *(float4*)(tout + ((size_t)b * NC + n) * ID + lane * 4) =
        make_float4(tx, ty, tz, tw);
}

// ---------------------------------------------------------------------------
// Fused logits (128i x 32n, K=256) -> softmax over n -> aggregate.
// Us double-buffered; next chunk's global loads issue before compute.
__global__ __launch_bounds__(256) void k_route(const float* __restrict__ u,
                                               const float* __restrict__ t,
                                               float* __restrict__ sp) {
    const int c = blockIdx.x, b = blockIdx.y;
    const int iBase = c * RIT;
    __shared__ float Ts[ID][36];        // t[b] transposed: Ts[k][n]
    __shared__ float cl[RIT][36];       // logits -> coefficients
    __shared__ float Us[2][16][132];    // double-buffered u chunk (transposed)
    const int tid = threadIdx.x;

    // Ts[k][n] = t[b][n][k]
    {
        const float* tb = t + (size_t)b * NC * ID;
#pragma unroll
        for (int n = 0; n < NC; ++n) Ts[tid][n] = tb[(size_t)n * ID + tid];
    }

    const int q = tid >> 3, r = tid & 7;
    const int si = tid >> 2, sc4 = tid & 3;       // staging role: i, k-quad
    const float* ub = u + ((size_t)b * IN + iBase) * ID;

    // prologue: chunk 0 into buffer 0
    {
        const float4 p0 = *(const float4*)(ub + (size_t)si * ID + sc4 * 4);
        const float4 p1 = *(const float4*)(ub + (size_t)(64 + si) * ID + sc4 * 4);
        Us[0][sc4 * 4 + 0][si] = p0.x;  Us[0][sc4 * 4 + 1][si] = p0.y;
        Us[0][sc4 * 4 + 2][si] = p0.z;  Us[0][sc4 * 4 + 3][si] = p0.w;
        Us[0][sc4 * 4 + 0][64 + si] = p1.x;  Us[0][sc4 * 4 + 1][64 + si] = p1.y;
        Us[0][sc4 * 4 + 2][64 + si] = p1.z;  Us[0][sc4 * 4 + 3][64 + si] = p1.w;
    }

    float acc4[4][4] = {{0.f}};
#pragma unroll 2
    for (int kc = 0; kc < ID / 16; ++kc) {
        __syncthreads();   // buffer kc&1 ready; buffer (kc+1)&1 free
        const int cb = kc & 1, nb = cb ^ 1;
        float4 p0, p1;
        if (kc < ID / 16 - 1) {   // issue next chunk's loads before compute
            p0 = *(const float4*)(ub + (size_t)si * ID + (kc + 1) * 16 + sc4 * 4);
            p1 = *(const float4*)(ub + (size_t)(64 + si) * ID + (kc + 1) * 16 + sc4 * 4);
        }
#pragma unroll
        for (int k = 0; k < 16; ++k) {
            const float4 a4 = *(const float4*)&Us[cb][k][q * 4];
            const float4 b4 = *(const float4*)&Ts[kc * 16 + k][r * 4];
            const float av[4] = {a4.x, a4.y, a4.z, a4.w};
            const float bv[4] = {b4.x, b4.y, b4.z, b4.w};
#pragma unroll
            for (int ii = 0; ii < 4; ++ii)
#pragma unroll
                for (int jj = 0; jj < 4; ++jj) acc4[ii][jj] += av[ii] * bv[jj];
        }
        if (kc < ID / 16 - 1) {
            Us[nb][sc4 * 4 + 0][si] = p0.x;  Us[nb][sc4 * 4 + 1][si] = p0.y;
            Us[nb][sc4 * 4 + 2][si] = p0.z;  Us[nb][sc4 * 4 + 3][si] = p0.w;
            Us[nb][sc4 * 4 + 0][64 + si] = p1.x;  Us[nb][sc4 * 4 + 1][64 + si] = p1.y;
            Us[nb][sc4 * 4 + 2][64 + si] = p1.z;  Us[nb][sc4 * 4 + 3][64 + si] = p1.w;
        }
    }
#pragma unroll
    for (int ii = 0; ii < 4; ++ii)
#pragma unroll
        for (int jj = 0; jj < 4; ++jj)
            cl[q * 4 + ii][r * 4 + jj] = acc4[ii][jj];
    __syncthreads();

    // softmax over 32 n per i (2 threads/i)
    {
        const int i = tid >> 1, half = tid & 1;
        float v[16];
#pragma unroll
        for (int j = 0; j < 16; ++j) v[j] = cl[i][half * 16 + j];
        float mx = v[0];
#pragma unroll
        for (int j = 1; j < 16; ++j) mx = fmaxf(mx, v[j]);
        mx = fmaxf(mx, __shfl_xor(mx, 1));
        float sum = 0.f;
#pragma unroll
        for (int j = 0; j < 16; ++j) { v[j] = __expf(v[j] - mx); sum += v[j]; }
        sum += __shfl_xor(sum, 1);
        const float inv = 1.0f / sum;
#pragma unroll
        for (int j = 0; j < 16; ++j) cl[i][half * 16 + j] = v[j] * inv;
    }
    __syncthreads();

    // aggregate: thread owns 4 d (float4) x 8 n (ng wave-uniform -> broadcast)
    const int d4 = tid & 63;
    const int ng = tid >> 6;
    float acc[8][4] = {{0.f}};
    const float* up = ub + d4 * 4;
#pragma unroll 4
    for (int i = 0; i < RIT; ++i) {
        const float4 uv = *(const float4*)(up + (size_t)i * ID);
        const float4 c0 = *(const float4*)&cl[i][ng * 8];
        const float4 c1 = *(const float4*)&cl[i][ng * 8 + 4];
        const float cv[8] = {c0.x, c0.y, c0.z, c0.w, c1.x, c1.y, c1.z, c1.w};
        const float uvv[4] = {uv.x, uv.y, uv.z, uv.w};
#pragma unroll
        for (int j = 0; j < 8; ++j)
#pragma unroll
            for (int x = 0; x < 4; ++x) acc[j][x] += cv[j] * uvv[x];
    }
    float* spb = sp + (size_t)(c * B + b) * NC * ID;
#pragma unroll
    for (int j = 0; j < 8; ++j)
        *(float4*)&spb[(size_t)(ng * 8 + j) * ID + d4 * 4] =
            make_float4(acc[j][0], acc[j][1], acc[j][2], acc[j][3]);
}

// ---------------------------------------------------------------------------
extern "C" void kernel_launch(void* const* d_in, const int* in_sizes, int n_in,
                              void* d_out, int out_size, void* d_ws, size_t ws_size,
                              hipStream_t stream) {
    const float* u = (const float*)d_in[0];   // [B][IN][ID]
    const float* W = (const float*)d_in[1];   // [NC*DC][ID]
    float* out = (float*)d_out;               // [B][NC][DC]

    float* ws  = (float*)d_ws;
    float* t   = ws;                                   // B*NC*ID    = 2 MB
    float* sp  = t  + (size_t)B * NC * ID;             // CH*B*NC*ID = 16 MB
    float* sp0 = sp + (size_t)CH * B * NC * ID;        // CH*B*ID    = 0.5 MB

    const dim3 blk(256);

    // iteration 0 (uniform c = 1/32)
    k_sumu <<<dim3(CH, B),     blk, 0, stream>>>(u, sp0);
    k_ot   <<<dim3(NC, B / 4), blk, 0, stream>>>(W, sp0, t, 0);
    // iteration 1
    k_route<<<dim3(CH, B),     blk, 0, stream>>>(u, t, sp);
    k_ot   <<<dim3(NC, B / 4), blk, 0, stream>>>(W, sp, t, 1);
    // iteration 2
    k_route<<<dim3(CH, B),     blk, 0, stream>>>(u, t, sp);
    k_ot   <<<dim3(NC, B / 4), blk, 0, stream>>>(W, sp, out, 2);
}